// Round 10
// baseline (223.110 us; speedup 1.0000x reference)
//
#include <hip/hip_runtime.h>
#include <hip/hip_bf16.h>
#include <math.h>

#define NV  10
#define H1  64
#define H2  32

typedef __attribute__((ext_vector_type(8))) short bf16x8;
typedef __attribute__((ext_vector_type(4))) float f32x4;
typedef __attribute__((ext_vector_type(4))) unsigned int u32x4;

union frag_u { bf16x8 f; u32x4 u; unsigned int w[4]; };

#define MFMA(a,b,c) __builtin_amdgcn_mfma_f32_16x16x32_bf16(a, b, c, 0, 0, 0)

__device__ __forceinline__ unsigned short f2bf(float f) {
    union { __hip_bfloat16 h; unsigned short u; } cv;
    cv.h = __float2bfloat16(f);   // RNE; compiler lowers pairs to v_cvt_pk_bf16_f32
    return cv.u;
}
__device__ __forceinline__ unsigned int pack2(float lo, float hi) {
    return (unsigned)f2bf(lo) | ((unsigned)f2bf(hi) << 16);
}

// GELU: deg-11 odd poly for erf(x/sqrt2) on [-3,3]; |x|>3 -> max(x,0).
// 12-14 full-rate VALU ops, no TRANS, no LDS. (identical to round 8)
__device__ __forceinline__ float gelu_poly(float x) {
    float p  = __builtin_amdgcn_fmed3f(x, -3.0f, 3.0f);
    float p2 = p * p;
    float t  = __builtin_fmaf(p2, -4.6113e-6f,    1.47439e-4f);
    t        = __builtin_fmaf(p2, t, -2.136050e-3f);
    t        = __builtin_fmaf(p2, t,  1.966256e-2f);
    t        = __builtin_fmaf(p2, t, -1.3288786e-1f);
    t        = __builtin_fmaf(p2, t,  7.9788456e-1f);
    float P  = p * t;
    float hx = 0.5f * x;
    float y  = __builtin_fmaf(hx, P, hx);
    float big = fmaxf(x, 0.0f);
    return (__builtin_fabsf(x) > 3.0f) ? big : y;
}

// ---------------------------------------------------------------------------
// Prep (1 block): adjacency mask -> Wout; W1 (adjacency+bias folded) and W2
// rearranged into exact MFMA A-fragment order as bf16 in ws. (round-8 layout)
// ---------------------------------------------------------------------------
__global__ void prep_W(const float* __restrict__ Wl,
                       const float* __restrict__ W1,
                       const float* __restrict__ b1,
                       const float* __restrict__ W2,
                       float* __restrict__ Wout,
                       unsigned short* __restrict__ a1,
                       unsigned short* __restrict__ a2) {
    __shared__ float W[100];
    __shared__ float thrv;
    int t = threadIdx.x;   // 256 threads
    if (t < 100) {
        int i = t / NV, j = t % NV;
        float w = 1.0f / (1.0f + expf(-Wl[t]));
        if (i == j) w = 0.0f;
        W[t] = w;
    }
    __syncthreads();
    if (t < 100) {
        float v = W[t];
        int cnt = 0;
        #pragma unroll
        for (int k = 0; k < 100; ++k) cnt += (W[k] > v) ? 1 : 0;
        if (cnt == 29) thrv = v;   // exactly 29 strictly greater == 30th largest
    }
    __syncthreads();
    if (t < 100) {
        float v = W[t];
        float m = (v >= thrv) ? v : 0.0f;
        Wout[t] = m;
        W[t] = m;
    }
    __syncthreads();
    // a1 fragments: row h=16t+(lane&15), k=(lane>>4)*8+b; k==10 is the bias slot
    for (int n = t; n < 20480; n += 256) {
        int b = n & 7, l = (n >> 3) & 63, tt = (n >> 9) & 3, j = n >> 11;
        int h = 16 * tt + (l & 15);
        int k = ((l >> 4) << 3) + b;
        float val = 0.0f;
        if (k < 10)       val = W1[j * 640 + h * 10 + k] * W[k * NV + j];
        else if (k == 10) val = b1[j * 64 + h];
        a1[n] = f2bf(val);
    }
    // a2 fragments: row o=16t2+(lane&15), h=32ks+(lane>>4)*8+b
    for (int n = t; n < 20480; n += 256) {
        int b = n & 7, l = (n >> 3) & 63, ks = (n >> 9) & 1, t2 = (n >> 10) & 1, j = n >> 11;
        int o = 16 * t2 + (l & 15);
        int h = 32 * ks + ((l >> 4) << 3) + b;
        a2[n] = f2bf(W2[j * 2048 + o * 64 + h]);
    }
}

// ---------------------------------------------------------------------------
// Main: each wave owns ONE j for its lifetime and grid-strides over 16-sample
// tiles. All weights for that j live in registers: 8 A-frags (32 VGPR),
// b2/W3 float4 slices, b3[j]. Round 8 re-streamed the same 80KB of frags
// from L2 every (tile,j): 2.5 GB of L2 traffic (~72us at 34.5 TB/s) -- now
// loaded once per wave (~80 MB total). Waves fully independent, no barriers.
// Handoff between GEMMs: per-wave 2KB swizzled LDS round-trip (round 8).
// ---------------------------------------------------------------------------
__global__ __launch_bounds__(256, 4) void ncd_mfma(
    const float* __restrict__ X,            // [B,10]
    const unsigned short* __restrict__ a1u, // frag-ordered W1eff+bias (bf16)
    const unsigned short* __restrict__ a2u, // frag-ordered W2 (bf16)
    const float* __restrict__ b2,           // [10,32]
    const float* __restrict__ W3,           // [10,32]
    const float* __restrict__ b3,           // [10]
    float* __restrict__ out,                // [B,10]
    int Bn, int ntiles, int jstride)        // jstride = total_waves/10
{
    __shared__ unsigned xlds[4][512];       // per-wave 2KB handoff buffer

    const int wave = threadIdx.x >> 6;
    const int lane = threadIdx.x & 63;
    const int q = lane >> 4;
    const int s = lane & 15;

    const int gw = blockIdx.x * 4 + wave;   // global wave id
    const int j  = gw % NV;                 // this wave's MLP index
    const int t0 = gw / NV;                 // first tile

    // ---- hoist all j-weights into registers (once per wave) ----
    const bf16x8* A1 = (const bf16x8*)a1u;
    const bf16x8* A2 = (const bf16x8*)a2u;
    bf16x8 af1[4], af2[4];
    #pragma unroll
    for (int tt = 0; tt < 4; ++tt) af1[tt] = A1[(j * 4 + tt) * 64 + lane];
    #pragma unroll
    for (int t2 = 0; t2 < 2; ++t2)
        #pragma unroll
        for (int ks = 0; ks < 2; ++ks)
            af2[t2 * 2 + ks] = A2[((j * 2 + t2) * 2 + ks) * 64 + lane];
    float4 b2v[2], w3v[2];
    #pragma unroll
    for (int t2 = 0; t2 < 2; ++t2) {
        b2v[t2] = *(const float4*)(b2 + j * 32 + 16 * t2 + 4 * q);
        w3v[t2] = *(const float4*)(W3 + j * 32 + 16 * t2 + 4 * q);
    }
    const float b3j = b3[j];

    unsigned* wb = xlds[wave];
    const int sw = (s & 7) << 2;
    const f32x4 zf = {0.0f, 0.0f, 0.0f, 0.0f};

    #pragma unroll 1
    for (int tile = t0; tile < ntiles; tile += jstride) {
        const int sbase = tile * 16;

        // --- B-frag of GEMM1: X row s, k = q*8+b (k=10 -> bias slot 1.0) ---
        int row = sbase + s; if (row > Bn - 1) row = Bn - 1;
        const float* xr = X + (size_t)row * 10;
        frag_u xb;
        if (q == 0) {
            float2 v0 = *(const float2*)(xr + 0), v1 = *(const float2*)(xr + 2);
            float2 v2 = *(const float2*)(xr + 4), v3 = *(const float2*)(xr + 6);
            xb.w[0] = pack2(v0.x, v0.y); xb.w[1] = pack2(v1.x, v1.y);
            xb.w[2] = pack2(v2.x, v2.y); xb.w[3] = pack2(v3.x, v3.y);
        } else if (q == 1) {
            float2 v4 = *(const float2*)(xr + 8);
            xb.w[0] = pack2(v4.x, v4.y);
            xb.w[1] = pack2(1.0f, 0.0f);          // k=10: bias slot
            xb.w[2] = 0u; xb.w[3] = 0u;
        } else {
            xb.w[0] = xb.w[1] = xb.w[2] = xb.w[3] = 0u;
        }

        // --- GEMM1: 4 h-tiles ---
        f32x4 acc[4];
        #pragma unroll
        for (int tt = 0; tt < 4; ++tt) acc[tt] = MFMA(af1[tt], xb.f, zf);

        // --- GELU + pack + swizzled per-wave LDS write ---
        #pragma unroll
        for (int tt = 0; tt < 4; ++tt) {
            float g0 = gelu_poly(acc[tt][0]);
            float g1 = gelu_poly(acc[tt][1]);
            float g2 = gelu_poly(acc[tt][2]);
            float g3 = gelu_poly(acc[tt][3]);
            int w0 = 8 * tt + 2 * q;
            wb[s * 32 + ((w0    ) ^ sw)] = pack2(g0, g1);
            wb[s * 32 + ((w0 + 1) ^ sw)] = pack2(g2, g3);
        }

        // --- GEMM2: 2 o-tiles x 2 K-steps ---
        f32x4 acc2[2] = {zf, zf};
        #pragma unroll
        for (int ks = 0; ks < 2; ++ks) {
            frag_u bfg;
            bfg.u = *(const u32x4*)&wb[s * 32 + ((16 * ks + 4 * q) ^ sw)];
            #pragma unroll
            for (int t2 = 0; t2 < 2; ++t2)
                acc2[t2] = MFMA(af2[t2 * 2 + ks], bfg.f, acc2[t2]);
        }

        // --- bias + GELU + head dot + quarter-lane reduce ---
        float partial = 0.0f;
        #pragma unroll
        for (int t2 = 0; t2 < 2; ++t2) {
            partial += gelu_poly(acc2[t2][0] + b2v[t2].x) * w3v[t2].x;
            partial += gelu_poly(acc2[t2][1] + b2v[t2].y) * w3v[t2].y;
            partial += gelu_poly(acc2[t2][2] + b2v[t2].z) * w3v[t2].z;
            partial += gelu_poly(acc2[t2][3] + b2v[t2].w) * w3v[t2].w;
        }
        partial += __shfl_xor(partial, 16);
        partial += __shfl_xor(partial, 32);
        float rj = partial + b3j;
        if (lane < 16 && sbase + lane < Bn) {
            out[(size_t)(sbase + lane) * 10 + j] = rj;
        }
    }
}

extern "C" void kernel_launch(void* const* d_in, const int* in_sizes, int n_in,
                              void* d_out, int out_size, void* d_ws, size_t ws_size,
                              hipStream_t stream) {
    const float* X  = (const float*)d_in[0];
    const float* Wl = (const float*)d_in[1];
    const float* W1 = (const float*)d_in[2];
    const float* b1 = (const float*)d_in[3];
    const float* W2 = (const float*)d_in[4];
    const float* b2 = (const float*)d_in[5];
    const float* W3 = (const float*)d_in[6];
    const float* b3 = (const float*)d_in[7];
    float* out = (float*)d_out;

    int B = in_sizes[0] / NV;                 // 500000
    float* Wout = out + (size_t)B * NV;       // output #2 (10x10 W) at the tail
    unsigned short* a1 = (unsigned short*)d_ws;        // 20480 bf16 = 40KB
    unsigned short* a2 = a1 + 20480;                   // 20480 bf16 = 40KB

    hipLaunchKernelGGL(prep_W, dim3(1), dim3(256), 0, stream,
                       Wl, W1, b1, W2, Wout, a1, a2);

    int ntiles = (B + 15) / 16;               // 31250
    const int blocks = 2560;                  // 10240 waves; multiple of 5 so
    const int jstride = blocks * 4 / NV;      // the per-j tile stride is exact
    hipLaunchKernelGGL(ncd_mfma, dim3(blocks), dim3(256), 0, stream,
                       X, a1, a2, b2, W3, b3, out, B, ntiles, jstride);
}

// Round 11
// 219.352 us; speedup vs baseline: 1.0171x; 1.0171x over previous
//
#include <hip/hip_runtime.h>
#include <hip/hip_bf16.h>
#include <math.h>

#define NV  10
#define H1  64
#define H2  32

typedef __attribute__((ext_vector_type(8))) short bf16x8;
typedef __attribute__((ext_vector_type(4))) float f32x4;
typedef __attribute__((ext_vector_type(4))) unsigned int u32x4;

union frag_u { bf16x8 f; u32x4 u; unsigned int w[4]; };

#define MFMA(a,b,c) __builtin_amdgcn_mfma_f32_16x16x32_bf16(a, b, c, 0, 0, 0)

__device__ __forceinline__ unsigned short f2bf(float f) {
    union { __hip_bfloat16 h; unsigned short u; } cv;
    cv.h = __float2bfloat16(f);   // RNE; pairs lower to v_cvt_pk_bf16_f32
    return cv.u;
}
__device__ __forceinline__ unsigned int pack2(float lo, float hi) {
    return (unsigned)f2bf(lo) | ((unsigned)f2bf(hi) << 16);
}

// GELU: deg-11 odd poly for erf(x/sqrt2) on [-3,3]; |x|>3 -> max(x,0).
// 13-14 full-rate VALU ops, no TRANS, no LDS. (identical to rounds 8/9)
__device__ __forceinline__ float gelu_poly(float x) {
    float p  = __builtin_amdgcn_fmed3f(x, -3.0f, 3.0f);
    float p2 = p * p;
    float t  = __builtin_fmaf(p2, -4.6113e-6f,    1.47439e-4f);
    t        = __builtin_fmaf(p2, t, -2.136050e-3f);
    t        = __builtin_fmaf(p2, t,  1.966256e-2f);
    t        = __builtin_fmaf(p2, t, -1.3288786e-1f);
    t        = __builtin_fmaf(p2, t,  7.9788456e-1f);
    float P  = p * t;
    float hx = 0.5f * x;
    float y  = __builtin_fmaf(hx, P, hx);
    float big = fmaxf(x, 0.0f);
    return (__builtin_fabsf(x) > 3.0f) ? big : y;
}

// ---------------------------------------------------------------------------
// Prep (1 block): adjacency mask -> Wout; W1 (adjacency+bias folded) and W2
// rearranged into exact MFMA A-fragment order as bf16 in ws. (round-8 layout)
// ---------------------------------------------------------------------------
__global__ void prep_W(const float* __restrict__ Wl,
                       const float* __restrict__ W1,
                       const float* __restrict__ b1,
                       const float* __restrict__ W2,
                       float* __restrict__ Wout,
                       unsigned short* __restrict__ a1,
                       unsigned short* __restrict__ a2) {
    __shared__ float W[100];
    __shared__ float thrv;
    int t = threadIdx.x;   // 256 threads
    if (t < 100) {
        int i = t / NV, j = t % NV;
        float w = 1.0f / (1.0f + expf(-Wl[t]));
        if (i == j) w = 0.0f;
        W[t] = w;
    }
    __syncthreads();
    if (t < 100) {
        float v = W[t];
        int cnt = 0;
        #pragma unroll
        for (int k = 0; k < 100; ++k) cnt += (W[k] > v) ? 1 : 0;
        if (cnt == 29) thrv = v;   // exactly 29 strictly greater == 30th largest
    }
    __syncthreads();
    if (t < 100) {
        float v = W[t];
        float m = (v >= thrv) ? v : 0.0f;
        Wout[t] = m;
        W[t] = m;
    }
    __syncthreads();
    // a1 fragments: row h=16t+(lane&15), k=(lane>>4)*8+b; k==10 is the bias slot
    for (int n = t; n < 20480; n += 256) {
        int b = n & 7, l = (n >> 3) & 63, tt = (n >> 9) & 3, j = n >> 11;
        int h = 16 * tt + (l & 15);
        int k = ((l >> 4) << 3) + b;
        float val = 0.0f;
        if (k < 10)       val = W1[j * 640 + h * 10 + k] * W[k * NV + j];
        else if (k == 10) val = b1[j * 64 + h];
        a1[n] = f2bf(val);
    }
    // a2 fragments: row o=16t2+(lane&15), h=32ks+(lane>>4)*8+b
    for (int n = t; n < 20480; n += 256) {
        int b = n & 7, l = (n >> 3) & 63, ks = (n >> 9) & 1, t2 = (n >> 10) & 1, j = n >> 11;
        int o = 16 * t2 + (l & 15);
        int h = 32 * ks + ((l >> 4) << 3) + b;
        a2[n] = f2bf(W2[j * 2048 + o * 64 + h]);
    }
}

// ---------------------------------------------------------------------------
// Main: each wave owns ONE j, grid-strides over 16-sample tiles; all weights
// for that j in registers (8 A-frags, b2/W3 slices, b3[j]).
// Round 9 -> 10 single-variable change: grid 2560 -> 9765 blocks (~8 tiles
// per wave instead of ~30). Round 8 vs 9 A/B showed occupancy (78% vs 39%)
// dominates weight-reload traffic; this keeps the hoist AND the occupancy.
// ---------------------------------------------------------------------------
__global__ __launch_bounds__(256, 4) void ncd_mfma(
    const float* __restrict__ X,            // [B,10]
    const unsigned short* __restrict__ a1u, // frag-ordered W1eff+bias (bf16)
    const unsigned short* __restrict__ a2u, // frag-ordered W2 (bf16)
    const float* __restrict__ b2,           // [10,32]
    const float* __restrict__ W3,           // [10,32]
    const float* __restrict__ b3,           // [10]
    float* __restrict__ out,                // [B,10]
    int Bn, int ntiles, int jstride)        // jstride = total_waves/10
{
    __shared__ unsigned xlds[4][512];       // per-wave 2KB handoff buffer

    const int wave = threadIdx.x >> 6;
    const int lane = threadIdx.x & 63;
    const int q = lane >> 4;
    const int s = lane & 15;

    const int gw = blockIdx.x * 4 + wave;   // global wave id
    const int j  = gw % NV;                 // this wave's MLP index
    const int t0 = gw / NV;                 // first tile

    // ---- hoist all j-weights into registers (once per wave) ----
    const bf16x8* A1 = (const bf16x8*)a1u;
    const bf16x8* A2 = (const bf16x8*)a2u;
    bf16x8 af1[4], af2[4];
    #pragma unroll
    for (int tt = 0; tt < 4; ++tt) af1[tt] = A1[(j * 4 + tt) * 64 + lane];
    #pragma unroll
    for (int t2 = 0; t2 < 2; ++t2)
        #pragma unroll
        for (int ks = 0; ks < 2; ++ks)
            af2[t2 * 2 + ks] = A2[((j * 2 + t2) * 2 + ks) * 64 + lane];
    float4 b2v[2], w3v[2];
    #pragma unroll
    for (int t2 = 0; t2 < 2; ++t2) {
        b2v[t2] = *(const float4*)(b2 + j * 32 + 16 * t2 + 4 * q);
        w3v[t2] = *(const float4*)(W3 + j * 32 + 16 * t2 + 4 * q);
    }
    const float b3j = b3[j];

    unsigned* wb = xlds[wave];
    const int sw = (s & 7) << 2;
    const f32x4 zf = {0.0f, 0.0f, 0.0f, 0.0f};

    #pragma unroll 1
    for (int tile = t0; tile < ntiles; tile += jstride) {
        const int sbase = tile * 16;

        // --- B-frag of GEMM1: X row s, k = q*8+b (k=10 -> bias slot 1.0) ---
        int row = sbase + s; if (row > Bn - 1) row = Bn - 1;
        const float* xr = X + (size_t)row * 10;
        frag_u xb;
        if (q == 0) {
            float2 v0 = *(const float2*)(xr + 0), v1 = *(const float2*)(xr + 2);
            float2 v2 = *(const float2*)(xr + 4), v3 = *(const float2*)(xr + 6);
            xb.w[0] = pack2(v0.x, v0.y); xb.w[1] = pack2(v1.x, v1.y);
            xb.w[2] = pack2(v2.x, v2.y); xb.w[3] = pack2(v3.x, v3.y);
        } else if (q == 1) {
            float2 v4 = *(const float2*)(xr + 8);
            xb.w[0] = pack2(v4.x, v4.y);
            xb.w[1] = pack2(1.0f, 0.0f);          // k=10: bias slot
            xb.w[2] = 0u; xb.w[3] = 0u;
        } else {
            xb.w[0] = xb.w[1] = xb.w[2] = xb.w[3] = 0u;
        }

        // --- GEMM1: 4 h-tiles ---
        f32x4 acc[4];
        #pragma unroll
        for (int tt = 0; tt < 4; ++tt) acc[tt] = MFMA(af1[tt], xb.f, zf);

        // --- GELU + pack + swizzled per-wave LDS write ---
        #pragma unroll
        for (int tt = 0; tt < 4; ++tt) {
            float g0 = gelu_poly(acc[tt][0]);
            float g1 = gelu_poly(acc[tt][1]);
            float g2 = gelu_poly(acc[tt][2]);
            float g3 = gelu_poly(acc[tt][3]);
            int w0 = 8 * tt + 2 * q;
            wb[s * 32 + ((w0    ) ^ sw)] = pack2(g0, g1);
            wb[s * 32 + ((w0 + 1) ^ sw)] = pack2(g2, g3);
        }

        // --- GEMM2: 2 o-tiles x 2 K-steps ---
        f32x4 acc2[2] = {zf, zf};
        #pragma unroll
        for (int ks = 0; ks < 2; ++ks) {
            frag_u bfg;
            bfg.u = *(const u32x4*)&wb[s * 32 + ((16 * ks + 4 * q) ^ sw)];
            #pragma unroll
            for (int t2 = 0; t2 < 2; ++t2)
                acc2[t2] = MFMA(af2[t2 * 2 + ks], bfg.f, acc2[t2]);
        }

        // --- bias + GELU + head dot + quarter-lane reduce ---
        float partial = 0.0f;
        #pragma unroll
        for (int t2 = 0; t2 < 2; ++t2) {
            partial += gelu_poly(acc2[t2][0] + b2v[t2].x) * w3v[t2].x;
            partial += gelu_poly(acc2[t2][1] + b2v[t2].y) * w3v[t2].y;
            partial += gelu_poly(acc2[t2][2] + b2v[t2].z) * w3v[t2].z;
            partial += gelu_poly(acc2[t2][3] + b2v[t2].w) * w3v[t2].w;
        }
        partial += __shfl_xor(partial, 16);
        partial += __shfl_xor(partial, 32);
        float rj = partial + b3j;
        if (lane < 16 && sbase + lane < Bn) {
            out[(size_t)(sbase + lane) * 10 + j] = rj;
        }
    }
}

extern "C" void kernel_launch(void* const* d_in, const int* in_sizes, int n_in,
                              void* d_out, int out_size, void* d_ws, size_t ws_size,
                              hipStream_t stream) {
    const float* X  = (const float*)d_in[0];
    const float* Wl = (const float*)d_in[1];
    const float* W1 = (const float*)d_in[2];
    const float* b1 = (const float*)d_in[3];
    const float* W2 = (const float*)d_in[4];
    const float* b2 = (const float*)d_in[5];
    const float* W3 = (const float*)d_in[6];
    const float* b3 = (const float*)d_in[7];
    float* out = (float*)d_out;

    int B = in_sizes[0] / NV;                 // 500000
    float* Wout = out + (size_t)B * NV;       // output #2 (10x10 W) at the tail
    unsigned short* a1 = (unsigned short*)d_ws;        // 20480 bf16 = 40KB
    unsigned short* a2 = a1 + 20480;                   // 20480 bf16 = 40KB

    hipLaunchKernelGGL(prep_W, dim3(1), dim3(256), 0, stream,
                       Wl, W1, b1, W2, Wout, a1, a2);

    int ntiles = (B + 15) / 16;               // 31250
    const int blocks = 9765;                  // 39060 waves (mult of 5): ~8 tiles/wave,
    const int jstride = blocks * 4 / NV;      // full occupancy (8 blocks/CU resident)
    hipLaunchKernelGGL(ncd_mfma, dim3(blocks), dim3(256), 0, stream,
                       X, a1, a2, b2, W3, b3, out, B, ntiles, jstride);
}